// Round 1
// baseline (723.616 us; speedup 1.0000x reference)
//
#include <hip/hip_runtime.h>

#define BATCHN 256
#define TSTEPS 199          // MAX_STEP - 1
#define NQ     1000
#define NROWS  (BATCHN * TSTEPS)   // 50944
#define ROWS_PER_BLOCK 4
#define NBLOCKS (NROWS / ROWS_PER_BLOCK)   // 12736, exact

// ws layout (floats): [0..255] masked bce sum per batch, [256..511] masked row count per batch
__global__ void zero_ws_kernel(float* __restrict__ ws) {
    int i = threadIdx.x;
    if (i < 2 * BATCHN) ws[i] = 0.0f;
}

// One wave (64 lanes) per row: mask via __ballot (no LDS, no __syncthreads),
// 8 float4 loads in flight per lane, stores overlap the log computation.
__global__ __launch_bounds__(256) void main_kernel(
    const float* __restrict__ pred,
    const float* __restrict__ batch,
    float* __restrict__ out,
    float* __restrict__ ws)
{
    const int wid  = threadIdx.x >> 6;
    const int lane = threadIdx.x & 63;
    const int r = blockIdx.x * ROWS_PER_BLOCK + wid;   // row 0..NROWS-1
    const int b = r / TSTEPS;
    const int t = r - b * TSTEPS;

    const float4* p4 = (const float4*)(pred + (size_t)r * NQ);
    const float4* g4 = (const float4*)(batch + ((size_t)b * 200 + t + 1) * NQ);

    // Issue all loads up front (row = 250 float4; lane covers k = lane + 64j)
    float4 p[4], g[4];
    #pragma unroll
    for (int j = 0; j < 4; ++j) {
        const int k = lane + 64 * j;
        if (k < 250) { g[j] = g4[k]; p[j] = p4[k]; }
        else         { g[j] = make_float4(0.f,0.f,0.f,0.f); p[j] = make_float4(0.f,0.f,0.f,0.f); }
    }

    // Row mask: any(gt == 1) across the wave — single ballot, no barrier.
    int any = 0;
    #pragma unroll
    for (int j = 0; j < 4; ++j)
        any |= (g[j].x == 1.0f) | (g[j].y == 1.0f) | (g[j].z == 1.0f) | (g[j].w == 1.0f);
    const unsigned long long bm = __ballot(any);
    const float m = bm ? 1.0f : 0.0f;

    float* out_pred = out + 1;
    float* out_gt   = out + 1 + (size_t)NROWS * NQ;
    float* out_mask = out + 1 + 2 * (size_t)NROWS * NQ;

    float s = 0.0f;
    #pragma unroll
    for (int j = 0; j < 4; ++j) {
        const int k = lane + 64 * j;
        if (k < 250) {
            float pe[4] = {p[j].x, p[j].y, p[j].z, p[j].w};
            float ge[4] = {g[j].x, g[j].y, g[j].z, g[j].w};
            const size_t o = (size_t)r * NQ + 4 * (size_t)k;
            #pragma unroll
            for (int q = 0; q < 4; ++q) {
                const float lp = fmaxf(__logf(pe[q]),        -100.0f);
                const float l1 = fmaxf(__logf(1.0f - pe[q]), -100.0f);
                // bce = -(g*lp + (1-g)*l1) = -(l1 + g*(lp - l1))
                s -= l1 + ge[q] * (lp - l1);
                __builtin_nontemporal_store(pe[q] * m, &out_pred[o + q]);
                __builtin_nontemporal_store(ge[q] * m, &out_gt[o + q]);
            }
        }
    }

    // Wave-level sum reduction (lane 0 gets the row total)
    #pragma unroll
    for (int off = 32; off > 0; off >>= 1) s += __shfl_down(s, off);

    if (lane == 0) {
        out_mask[r] = m;
        if (bm) {
            atomicAdd(&ws[b], s);
            atomicAdd(&ws[BATCHN + b], 1.0f);
        }
    }
}

__global__ __launch_bounds__(256) void final_kernel(
    float* __restrict__ out, const float* __restrict__ ws)
{
    const int b = threadIdx.x;  // 0..255 (one per batch element)
    // cnt >= 1 guaranteed: batch[:,1,0] == 1 so t=0 row is always masked
    float per = ws[b] / (ws[BATCHN + b] * (float)NQ);

    #pragma unroll
    for (int off = 32; off > 0; off >>= 1) per += __shfl_down(per, off);

    __shared__ float ssum[4];
    const int lane = b & 63, wid = b >> 6;
    if (lane == 0) ssum[wid] = per;
    __syncthreads();
    if (b == 0) out[0] = ssum[0] + ssum[1] + ssum[2] + ssum[3];
}

extern "C" void kernel_launch(void* const* d_in, const int* in_sizes, int n_in,
                              void* d_out, int out_size, void* d_ws, size_t ws_size,
                              hipStream_t stream) {
    const float* pred  = (const float*)d_in[0];
    const float* batch = (const float*)d_in[1];
    float* out = (float*)d_out;
    float* ws  = (float*)d_ws;

    zero_ws_kernel<<<1, 512, 0, stream>>>(ws);
    main_kernel<<<NBLOCKS, 256, 0, stream>>>(pred, batch, out, ws);
    final_kernel<<<1, 256, 0, stream>>>(out, ws);
}

// Round 2
// 705.952 us; speedup vs baseline: 1.0250x; 1.0250x over previous
//
#include <hip/hip_runtime.h>

#define BATCHN 256
#define TSTEPS 199          // MAX_STEP - 1
#define NQ     1000
#define NROWS  (BATCHN * TSTEPS)   // 50944
#define RPB    4                   // rows (waves) per block
#define NBLOCKS (NROWS / RPB)      // 12736, exact
#define LSTRIDE 1008               // 1000 + pad, keeps 16B-aligned per-wave base (1008*4=4032)

// ws layout (floats): [0..255] masked bce sum per batch, [256..511] masked row count per batch
__global__ void zero_ws_kernel(float* __restrict__ ws) {
    int i = threadIdx.x;
    if (i < 2 * BATCHN) ws[i] = 0.0f;
}

// One wave per row. Row mask via __ballot (no barriers). Store realignment:
// out+1 is only 4B-aligned, so stage masked values in LDS (aligned b128 writes),
// read back shifted +3 floats, and emit aligned global_store_dwordx4 full-line
// stores for the body + 3-float head + 1-float tail.
__global__ __launch_bounds__(256) void main_kernel(
    const float* __restrict__ pred,
    const float* __restrict__ batch,
    float* __restrict__ out,
    float* __restrict__ ws)
{
    __shared__ float stage[RPB][LSTRIDE];

    const int wid  = threadIdx.x >> 6;
    const int lane = threadIdx.x & 63;
    const int r = blockIdx.x * RPB + wid;      // row 0..NROWS-1
    const int b = r / TSTEPS;
    const int t = r - b * TSTEPS;

    const float4* p4 = (const float4*)(pred + (size_t)r * NQ);
    const float4* g4 = (const float4*)(batch + ((size_t)b * 200 + t + 1) * NQ);

    // source groups k = lane + 64j, j=0..3; j=3 valid only for lane < 58 (250 groups)
    const bool full = lane < 58;
    const float4 z = make_float4(0.f, 0.f, 0.f, 0.f);

    float4 g0 = g4[lane], g1 = g4[lane + 64], g2 = g4[lane + 128];
    float4 g3 = full ? g4[lane + 192] : z;
    float4 p0 = p4[lane], p1 = p4[lane + 64], p2 = p4[lane + 128];
    float4 p3 = full ? p4[lane + 192] : z;   // p=0,g=0 contributes exactly 0 to s

    int any = (g0.x == 1.0f) | (g0.y == 1.0f) | (g0.z == 1.0f) | (g0.w == 1.0f)
            | (g1.x == 1.0f) | (g1.y == 1.0f) | (g1.z == 1.0f) | (g1.w == 1.0f)
            | (g2.x == 1.0f) | (g2.y == 1.0f) | (g2.z == 1.0f) | (g2.w == 1.0f)
            | (g3.x == 1.0f) | (g3.y == 1.0f) | (g3.z == 1.0f) | (g3.w == 1.0f);
    const unsigned long long bm = __ballot(any);
    const float m = bm ? 1.0f : 0.0f;

    // BCE partial sum (from registers; clamp before multiply so 0-fill lanes add 0)
    float s = 0.0f;
    {
        float pe[16] = {p0.x,p0.y,p0.z,p0.w, p1.x,p1.y,p1.z,p1.w,
                        p2.x,p2.y,p2.z,p2.w, p3.x,p3.y,p3.z,p3.w};
        float ge[16] = {g0.x,g0.y,g0.z,g0.w, g1.x,g1.y,g1.z,g1.w,
                        g2.x,g2.y,g2.z,g2.w, g3.x,g3.y,g3.z,g3.w};
        #pragma unroll
        for (int q = 0; q < 16; ++q) {
            const float lp = fmaxf(__logf(pe[q]),        -100.0f);
            const float l1 = fmaxf(__logf(1.0f - pe[q]), -100.0f);
            s -= l1 + ge[q] * (lp - l1);   // bce = -(l1 + g*(lp-l1))
        }
    }

    float* const orow_p = out + 1 + (size_t)r * NQ;
    float* const orow_g = out + 1 + (size_t)NROWS * NQ + (size_t)r * NQ;
    float* const out_mask = out + 1 + 2 * (size_t)NROWS * NQ;

    float4* const Ls = (float4*)&stage[wid][0];   // 16B-aligned per-wave base

    // ---- emit pred*m ----
    {
        Ls[lane]       = make_float4(p0.x*m, p0.y*m, p0.z*m, p0.w*m);
        Ls[lane + 64]  = make_float4(p1.x*m, p1.y*m, p1.z*m, p1.w*m);
        Ls[lane + 128] = make_float4(p2.x*m, p2.y*m, p2.z*m, p2.w*m);
        if (full) Ls[lane + 192] = make_float4(p3.x*m, p3.y*m, p3.z*m, p3.w*m);
        // same-wave DS ordering via lgkmcnt (compiler-inserted): no barrier needed
        #pragma unroll
        for (int j = 0; j < 4; ++j) {
            const int kp = lane + 64 * j;          // store group, kp < 249
            if (j < 3 || lane < 57) {
                float4 v = make_float4(stage[wid][3 + 4*kp], stage[wid][4 + 4*kp],
                                       stage[wid][5 + 4*kp], stage[wid][6 + 4*kp]);
                *(float4*)(orow_p + 3 + 4*kp) = v;   // global idx ≡ 0 mod 4: aligned
            }
        }
        if (lane >= 61) orow_p[lane - 61] = stage[wid][lane - 61];  // head e=0..2
        if (lane == 60) orow_p[999]       = stage[wid][999];        // tail e=999
    }

    // ---- emit gt*m (reuse buffer; WAR ordered by lgkmcnt) ----
    {
        Ls[lane]       = make_float4(g0.x*m, g0.y*m, g0.z*m, g0.w*m);
        Ls[lane + 64]  = make_float4(g1.x*m, g1.y*m, g1.z*m, g1.w*m);
        Ls[lane + 128] = make_float4(g2.x*m, g2.y*m, g2.z*m, g2.w*m);
        if (full) Ls[lane + 192] = make_float4(g3.x*m, g3.y*m, g3.z*m, g3.w*m);
        #pragma unroll
        for (int j = 0; j < 4; ++j) {
            const int kp = lane + 64 * j;
            if (j < 3 || lane < 57) {
                float4 v = make_float4(stage[wid][3 + 4*kp], stage[wid][4 + 4*kp],
                                       stage[wid][5 + 4*kp], stage[wid][6 + 4*kp]);
                *(float4*)(orow_g + 3 + 4*kp) = v;
            }
        }
        if (lane >= 61) orow_g[lane - 61] = stage[wid][lane - 61];
        if (lane == 60) orow_g[999]       = stage[wid][999];
    }

    // wave-level sum reduction (lane 0 gets the row total)
    #pragma unroll
    for (int off = 32; off > 0; off >>= 1) s += __shfl_down(s, off);

    if (lane == 0) {
        out_mask[r] = m;
        if (bm) {
            atomicAdd(&ws[b], s);
            atomicAdd(&ws[BATCHN + b], 1.0f);
        }
    }
}

__global__ __launch_bounds__(256) void final_kernel(
    float* __restrict__ out, const float* __restrict__ ws)
{
    const int b = threadIdx.x;  // 0..255 (one per batch element)
    // cnt >= 1 guaranteed: batch[:,1,0] == 1 so t=0 row is always masked
    float per = ws[b] / (ws[BATCHN + b] * (float)NQ);

    #pragma unroll
    for (int off = 32; off > 0; off >>= 1) per += __shfl_down(per, off);

    __shared__ float ssum[4];
    const int lane = b & 63, wid = b >> 6;
    if (lane == 0) ssum[wid] = per;
    __syncthreads();
    if (b == 0) out[0] = ssum[0] + ssum[1] + ssum[2] + ssum[3];
}

extern "C" void kernel_launch(void* const* d_in, const int* in_sizes, int n_in,
                              void* d_out, int out_size, void* d_ws, size_t ws_size,
                              hipStream_t stream) {
    const float* pred  = (const float*)d_in[0];
    const float* batch = (const float*)d_in[1];
    float* out = (float*)d_out;
    float* ws  = (float*)d_ws;

    zero_ws_kernel<<<1, 512, 0, stream>>>(ws);
    main_kernel<<<NBLOCKS, 256, 0, stream>>>(pred, batch, out, ws);
    final_kernel<<<1, 256, 0, stream>>>(out, ws);
}

// Round 5
// 696.301 us; speedup vs baseline: 1.0392x; 1.0139x over previous
//
#include <hip/hip_runtime.h>

#define BATCHN 256
#define TSTEPS 199          // MAX_STEP - 1
#define NQ     1000
#define NROWS  (BATCHN * TSTEPS)   // 50944
#define RPB    4                   // rows (waves) per block
#define NBLOCKS (NROWS / RPB)      // 12736, exact

// ws layout (floats): [0..255] masked bce sum per batch, [256..511] masked row count per batch
__global__ void zero_ws_kernel(float* __restrict__ ws) {
    int i = threadIdx.x;
    if (i < 2 * BATCHN) ws[i] = 0.0f;
}

// Store one masked row (1000 floats) to orow (orow is 4B-aligned, orow+3 is 16B-aligned).
// Groups: w_j = row elements [4k .. 4k+3], k = lane + 64*j (k=0..249; j=3 valid lane<58).
// Output body: aligned float4 at orow+3+4*kp = {w[kp].w, w[kp+1].x, w[kp+1].y, w[kp+1].z},
// kp = 0..248. Shift done with shuffles: w[kp+1] = shfl_down(w_j,1), lane63 -> lane0's w_{j+1}.
__device__ __forceinline__ void store_row_shifted(
    float* __restrict__ orow, const int lane,
    const float4 w0, const float4 w1, const float4 w2, const float4 w3)
{
    // lane0's next-group heads, for the lane-63 boundary
    const float b1x = __shfl(w1.x, 0), b1y = __shfl(w1.y, 0), b1z = __shfl(w1.z, 0);
    const float b2x = __shfl(w2.x, 0), b2y = __shfl(w2.y, 0), b2z = __shfl(w2.z, 0);
    const float b3x = __shfl(w3.x, 0), b3y = __shfl(w3.y, 0), b3z = __shfl(w3.z, 0);

    float n0x = __shfl_down(w0.x, 1), n0y = __shfl_down(w0.y, 1), n0z = __shfl_down(w0.z, 1);
    float n1x = __shfl_down(w1.x, 1), n1y = __shfl_down(w1.y, 1), n1z = __shfl_down(w1.z, 1);
    float n2x = __shfl_down(w2.x, 1), n2y = __shfl_down(w2.y, 1), n2z = __shfl_down(w2.z, 1);
    const float n3x = __shfl_down(w3.x, 1), n3y = __shfl_down(w3.y, 1), n3z = __shfl_down(w3.z, 1);
    if (lane == 63) {
        n0x = b1x; n0y = b1y; n0z = b1z;
        n1x = b2x; n1y = b2y; n1z = b2z;
        n2x = b3x; n2y = b3y; n2z = b3z;
    }

    *(float4*)(orow + 3 + 4 * lane)         = make_float4(w0.w, n0x, n0y, n0z);
    *(float4*)(orow + 3 + 4 * (lane + 64))  = make_float4(w1.w, n1x, n1y, n1z);
    *(float4*)(orow + 3 + 4 * (lane + 128)) = make_float4(w2.w, n2x, n2y, n2z);
    if (lane < 57)                            // kp = 192..248
        *(float4*)(orow + 3 + 4 * (lane + 192)) = make_float4(w3.w, n3x, n3y, n3z);

    if (lane == 0) { orow[0] = w0.x; orow[1] = w0.y; orow[2] = w0.z; }  // head e=0..2
    if (lane == 57) orow[999] = w3.w;                                    // tail e=999 (group 249 .w)
}

// One wave per row. Row mask via __ballot. No LDS, no barriers.
__global__ __launch_bounds__(256) void main_kernel(
    const float* __restrict__ pred,
    const float* __restrict__ batch,
    float* __restrict__ out,
    float* __restrict__ ws)
{
    const int wid  = threadIdx.x >> 6;
    const int lane = threadIdx.x & 63;
    const int r = blockIdx.x * RPB + wid;      // row 0..NROWS-1
    const int b = r / TSTEPS;
    const int t = r - b * TSTEPS;

    const float4* p4 = (const float4*)(pred + (size_t)r * NQ);
    const float4* g4 = (const float4*)(batch + ((size_t)b * 200 + t + 1) * NQ);

    const bool full = lane < 58;               // group 192+lane exists only for lane<58
    const float4 z = make_float4(0.f, 0.f, 0.f, 0.f);

    float4 g0 = g4[lane], g1 = g4[lane + 64], g2 = g4[lane + 128];
    float4 g3 = full ? g4[lane + 192] : z;
    float4 p0 = p4[lane], p1 = p4[lane + 64], p2 = p4[lane + 128];
    float4 p3 = full ? p4[lane + 192] : z;     // p=0,g=0 contributes exactly 0 to s

    int any = (g0.x == 1.0f) | (g0.y == 1.0f) | (g0.z == 1.0f) | (g0.w == 1.0f)
            | (g1.x == 1.0f) | (g1.y == 1.0f) | (g1.z == 1.0f) | (g1.w == 1.0f)
            | (g2.x == 1.0f) | (g2.y == 1.0f) | (g2.z == 1.0f) | (g2.w == 1.0f)
            | (g3.x == 1.0f) | (g3.y == 1.0f) | (g3.z == 1.0f) | (g3.w == 1.0f);
    const unsigned long long bm = __ballot(any);
    const float m = bm ? 1.0f : 0.0f;

    // BCE partial sum (clamp before multiply so zero-fill lanes add exactly 0)
    float s = 0.0f;
    {
        const float pe[16] = {p0.x,p0.y,p0.z,p0.w, p1.x,p1.y,p1.z,p1.w,
                              p2.x,p2.y,p2.z,p2.w, p3.x,p3.y,p3.z,p3.w};
        const float ge[16] = {g0.x,g0.y,g0.z,g0.w, g1.x,g1.y,g1.z,g1.w,
                              g2.x,g2.y,g2.z,g2.w, g3.x,g3.y,g3.z,g3.w};
        #pragma unroll
        for (int q = 0; q < 16; ++q) {
            const float lp = fmaxf(__logf(pe[q]),        -100.0f);
            const float l1 = fmaxf(__logf(1.0f - pe[q]), -100.0f);
            s -= l1 + ge[q] * (lp - l1);   // bce = -(l1 + g*(lp-l1))
        }
    }

    float* const orow_p   = out + 1 + (size_t)r * NQ;
    float* const orow_g   = out + 1 + (size_t)NROWS * NQ + (size_t)r * NQ;
    float* const out_mask = out + 1 + 2 * (size_t)NROWS * NQ;

    store_row_shifted(orow_p, lane,
        make_float4(p0.x*m, p0.y*m, p0.z*m, p0.w*m),
        make_float4(p1.x*m, p1.y*m, p1.z*m, p1.w*m),
        make_float4(p2.x*m, p2.y*m, p2.z*m, p2.w*m),
        make_float4(p3.x*m, p3.y*m, p3.z*m, p3.w*m));

    store_row_shifted(orow_g, lane,
        make_float4(g0.x*m, g0.y*m, g0.z*m, g0.w*m),
        make_float4(g1.x*m, g1.y*m, g1.z*m, g1.w*m),
        make_float4(g2.x*m, g2.y*m, g2.z*m, g2.w*m),
        make_float4(g3.x*m, g3.y*m, g3.z*m, g3.w*m));

    // wave-level sum reduction (lane 0 gets the row total)
    #pragma unroll
    for (int off = 32; off > 0; off >>= 1) s += __shfl_down(s, off);

    if (lane == 0) {
        out_mask[r] = m;
        if (bm) {
            atomicAdd(&ws[b], s);
            atomicAdd(&ws[BATCHN + b], 1.0f);
        }
    }
}

__global__ __launch_bounds__(256) void final_kernel(
    float* __restrict__ out, const float* __restrict__ ws)
{
    const int b = threadIdx.x;  // 0..255 (one per batch element)
    // cnt >= 1 guaranteed: batch[:,1,0] == 1 so t=0 row is always masked
    float per = ws[b] / (ws[BATCHN + b] * (float)NQ);

    #pragma unroll
    for (int off = 32; off > 0; off >>= 1) per += __shfl_down(per, off);

    __shared__ float ssum[4];
    const int lane = b & 63, wid = b >> 6;
    if (lane == 0) ssum[wid] = per;
    __syncthreads();
    if (b == 0) out[0] = ssum[0] + ssum[1] + ssum[2] + ssum[3];
}

extern "C" void kernel_launch(void* const* d_in, const int* in_sizes, int n_in,
                              void* d_out, int out_size, void* d_ws, size_t ws_size,
                              hipStream_t stream) {
    const float* pred  = (const float*)d_in[0];
    const float* batch = (const float*)d_in[1];
    float* out = (float*)d_out;
    float* ws  = (float*)d_ws;

    zero_ws_kernel<<<1, 512, 0, stream>>>(ws);
    main_kernel<<<NBLOCKS, 256, 0, stream>>>(pred, batch, out, ws);
    final_kernel<<<1, 256, 0, stream>>>(out, ws);
}